// Round 5
// baseline (299.185 us; speedup 1.0000x reference)
//
#include <hip/hip_runtime.h>

#define NPTS 50000
#define HN 32
#define INF1 128
#define OUTF3 256
#define MIDF 64
#define KP 15
#define EPSV 1e-6f
#define SLOPE 0.1f
#define KPE 0.48f   // 1.2 * 2.0 / 5.0
#define INVN (1.f / 50000.f)

typedef __attribute__((ext_vector_type(8))) short short8;   // 8 bf16
typedef __attribute__((ext_vector_type(4))) float float4v;  // MFMA acc
typedef unsigned short ushort;
typedef unsigned long long ull;

__device__ inline ushort f2bf(float f) {
    union { float f; unsigned u; } v; v.f = f;
    unsigned r = v.u + 0x7fff + ((v.u >> 16) & 1);
    return (ushort)(r >> 16);
}
__device__ inline float bf2f(ushort u) {
    union { unsigned u; float f; } v; v.u = ((unsigned)u) << 16;
    return v.f;
}
// pack 2 f32 -> 2 bf16 (RNE, bit-identical to f2bf) in ONE VALU instr
__device__ inline unsigned cvt_pk_bf16(float lo, float hi) {
    unsigned r;
    asm("v_cvt_pk_bf16_f32 %0, %1, %2" : "=v"(r) : "v"(lo), "v"(hi));
    return r;
}

// x1 rows are stored PERMUTED: mem offset m in [0,64) holds original feature
// d(m) = (m&3)*16 + (m>>2).  So a lane with dl = m>>2 reads one b64 (offsets
// 4dl..4dl+3) and gets features {dl, 16+dl, 32+dl, 48+dl} = the 4 B-frag
// elements (nt=0..3) it needs for the gather-MFMA.
//
// scb / x3b are LINEAR [n][256] (channel-major).  r1/r2 tried group-packed
// b64 layouts: measured +21us on the non-kpconv kernels vs r0's scalar
// stores + direct float4 k_final.  Reverted to the empirically faster r0
// layout.
//
// k_kpconv is the r2-exact version (passing).  __launch_bounds__(256,4)
// alone NaN'd it in r4 (compiler restructuring of the in-flight gather
// region) -- do NOT reintroduce it.

// ---------- repack all weights f32 -> B-fragment bf16 ----------
__global__ __launch_bounds__(256)
void k_repack_all(const float* __restrict__ w1, const float* __restrict__ wsw,
                  ushort* __restrict__ wpC,
                  const float* __restrict__ kw, ushort* __restrict__ wpk,
                  const float* __restrict__ w3, ushort* __restrict__ wp3) {
    int id = blockIdx.x * 256 + threadIdx.x;
    if (id < 5120) {                      // wpC: [w1|wsw] K=128 N=320
        int l = id & 63;
        int nt = (id >> 6) % 20, s = id / 1280;
        int n = nt * 16 + (l & 15);
        int k0 = s * 32 + ((l >> 4) & 3) * 8;
#pragma unroll
        for (int j = 0; j < 8; j++) {
            float v = (n < 64) ? w1[(k0 + j) * 64 + n] : wsw[(k0 + j) * 256 + (n - 64)];
            wpC[id * 8 + j] = f2bf(v);
        }
    } else if (id < 13312) {              // wpk: kd = d*16+k (k=15 -> 0), K=1024 N=64
        int id2 = id - 5120;
        int l2 = id2 & 63;
        int nt = (id2 >> 6) & 3, s = id2 >> 8;
        int n = nt * 16 + (l2 & 15);
        int kd0 = s * 32 + ((l2 >> 4) & 3) * 8;
#pragma unroll
        for (int j = 0; j < 8; j++) {
            int kd = kd0 + j, d = kd >> 4, kk = kd & 15;
            float v = (kk < KP) ? kw[kk * 4096 + d * 64 + n] : 0.f;
            wpk[id2 * 8 + j] = f2bf(v);
        }
    } else if (id < 15360) {              // wp3: K=64 N=256
        int id3 = id - 13312;
        int l3 = id3 & 63;
        int nt = (id3 >> 6) % 16, s = id3 / 1024;
        int n = nt * 16 + (l3 & 15);
        int k0 = s * 32 + ((l3 >> 4) & 3) * 8;
#pragma unroll
        for (int j = 0; j < 8; j++)
            wp3[id3 * 8 + j] = f2bf(w3[(k0 + j) * 256 + n]);
    }
}

// ---------- conv1 + shortcut fused GEMM; x1 permuted, scb LINEAR ----------
__global__ __launch_bounds__(256)
void k_conv1sc(const float* __restrict__ feat, const ushort* __restrict__ WpC,
               ushort* __restrict__ x1raw, ushort* __restrict__ scb,
               float* __restrict__ Sa1, float* __restrict__ Sq1,
               float* __restrict__ SaS, float* __restrict__ SqS, int M) {
    __shared__ float sred[320], qred[320];
    int t = threadIdx.x;
    int w = t >> 6, l = t & 63;
    int dl = l & 15, q4 = l >> 4;

    for (int c = t; c < 320; c += 256) { sred[c] = 0.f; qred[c] = 0.f; }
    __syncthreads();

    int m0 = blockIdx.x * 64 + w * 16;
    int row = m0 + dl;
    long arow = (row < M) ? row : (M - 1);
    const float* ap0 = feat + arow * INF1 + q4 * 8;
    short8 afr[4];
#pragma unroll
    for (int s = 0; s < 4; s++) {
        float4 a0 = *(const float4*)(ap0 + s * 32);
        float4 a1 = *(const float4*)(ap0 + s * 32 + 4);
        union { short8 v; unsigned d[4]; } au;
        au.d[0] = cvt_pk_bf16(a0.x, a0.y);
        au.d[1] = cvt_pk_bf16(a0.z, a0.w);
        au.d[2] = cvt_pk_bf16(a1.x, a1.y);
        au.d[3] = cvt_pk_bf16(a1.z, a1.w);
        afr[s] = au.v;
    }
    const short8* Bp = (const short8*)WpC + l;
    int rb = q4 * 4;
#pragma unroll
    for (int half = 0; half < 2; half++) {
        float4v acc[10];
#pragma unroll
        for (int j = 0; j < 10; j++) acc[j] = (float4v){0.f, 0.f, 0.f, 0.f};
#pragma unroll
        for (int s = 0; s < 4; s++)
#pragma unroll
            for (int j = 0; j < 10; j++) {
                short8 bf = Bp[(s * 20 + half * 10 + j) * 64];
                acc[j] = __builtin_amdgcn_mfma_f32_16x16x32_bf16(afr[s], bf, acc[j], 0, 0, 0);
            }
#pragma unroll
        for (int r = 0; r < 4; r++) {
            int rr = m0 + rb + r;
            if (rr < M) {
                if (half == 0) {
                    // j=0..3 are x1 cols c=j*16+dl -> permuted offset 4*dl+j, packed b64
                    uint2 pk;
                    pk.x = cvt_pk_bf16(acc[0][r], acc[1][r]);
                    pk.y = cvt_pk_bf16(acc[2][r], acc[3][r]);
                    *(uint2*)(x1raw + (long)rr * 64 + 4 * dl) = pk;
#pragma unroll
                    for (int j = 4; j < 10; j++)
                        scb[(long)rr * 256 + (j * 16 + dl - 64)] = f2bf(acc[j][r]);
                } else {
#pragma unroll
                    for (int j = 0; j < 10; j++)
                        scb[(long)rr * 256 + ((10 + j) * 16 + dl - 64)] = f2bf(acc[j][r]);
                }
            }
        }
#pragma unroll
        for (int j = 0; j < 10; j++) {
            float s = 0.f, q = 0.f;
#pragma unroll
            for (int r = 0; r < 4; r++) {
                float v = ((m0 + rb + r) < M) ? acc[j][r] : 0.f;
                s += v; q += v * v;
            }
            s += __shfl_xor(s, 16); s += __shfl_xor(s, 32);
            q += __shfl_xor(q, 16); q += __shfl_xor(q, 32);
            if (q4 == 0) {
                atomicAdd(&sred[(half * 10 + j) * 16 + dl], s);
                atomicAdd(&qred[(half * 10 + j) * 16 + dl], q);
            }
        }
    }
    __syncthreads();
    for (int c = t; c < 320; c += 256) {
        if (c < 64) { atomicAdd(&Sa1[c], sred[c]); atomicAdd(&Sq1[c], qred[c]); }
        else        { atomicAdd(&SaS[c - 64], sred[c]); atomicAdd(&SqS[c - 64], qred[c]); }
    }
}

// ---------- BN1 + lrelu on permuted x1 (channel = d(m)) ----------
__global__ __launch_bounds__(256)
void k_bnx(const ushort* __restrict__ X, ushort* __restrict__ Y,
           const float* __restrict__ Sa, const float* __restrict__ Sq,
           const float* __restrict__ g, const float* __restrict__ b) {
    __shared__ float sc[64], sh[64];
    int t = threadIdx.x;
    if (t < 64) {
        float m = Sa[t] * INVN;
        float v = Sq[t] * INVN - m * m;
        float s = g[t] * rsqrtf(v + EPSV);
        sc[t] = s; sh[t] = b[t] - s * m;
    }
    __syncthreads();
    int i = blockIdx.x * 256 + t;
    long base = (long)i * 4;
    int dlp = i & 15;           // m0 = 4*dlp; element j has channel j*16+dlp
    ull vin = *(const ull*)(X + base);
    float vv[4];
#pragma unroll
    for (int j = 0; j < 4; j++) {
        int c = j * 16 + dlp;
        float f = bf2f((ushort)((vin >> (16 * j)) & 0xffff));
        float v = f * sc[c] + sh[c];
        vv[j] = (v >= 0.f) ? v : SLOPE * v;
    }
    uint2 vo;
    vo.x = cvt_pk_bf16(vv[0], vv[1]);
    vo.y = cvt_pk_bf16(vv[2], vv[3]);
    *(uint2*)(Y + base) = vo;
}

// ---------- fused KPConv (r2-exact, passing): gather prefetch + all-MFMA ----------
__global__ __launch_bounds__(256)
void k_kpconv(const float* __restrict__ qpts, const float* __restrict__ spts,
              const int* __restrict__ nbr, const ushort* __restrict__ x1b,
              const float* __restrict__ kpp, const ushort* __restrict__ kwp,
              ushort* __restrict__ y, float* __restrict__ Sa, float* __restrict__ Sq) {
    __shared__ __align__(16) ushort wfs[16][1032];  // [p][kd], kd=d*16+k, pitch 1032
    __shared__ float posd[4][4][3][HN];             // [wave][pp][comp][h]

    int t = threadIdx.x;
    int w = t >> 6, l = t & 63;
    int dl = l & 15, q4 = l >> 4;

    int kmin = (dl < KP) ? dl : (KP - 1);
    float kx = kpp[kmin * 3 + 0], ky = kpp[kmin * 3 + 1], kz = kpp[kmin * 3 + 2];

    int nb = blockIdx.x * 16 + w * 4;   // first point of this wave

    // ---- prologue A: per-lane gather-index loads for ALL 4 points ----
    int idg[4][8];
#pragma unroll
    for (int pp = 0; pp < 4; pp++) {
        const int4* np = (const int4*)(nbr + (long)(nb + pp) * HN + q4 * 8);
        int4 ia = np[0], ib = np[1];
        idg[pp][0] = ia.x; idg[pp][1] = ia.y; idg[pp][2] = ia.z; idg[pp][3] = ia.w;
        idg[pp][4] = ib.x; idg[pp][5] = ib.y; idg[pp][6] = ib.z; idg[pp][7] = ib.w;
    }

    // ---- prologue B: posd setup, both half-waves (hf=0 -> pp0,1; hf=1 -> pp2,3) ----
    {
        int hh = l & 31, hf = l >> 5;
        float dx[2], dy[2], dz[2];
#pragma unroll
        for (int p2 = 0; p2 < 2; p2++) {
            int pp = hf * 2 + p2;
            int idx = nbr[(long)(nb + pp) * HN + hh];
            dx[p2] = spts[(long)idx * 3 + 0] - qpts[(nb + pp) * 3 + 0];
            dy[p2] = spts[(long)idx * 3 + 1] - qpts[(nb + pp) * 3 + 1];
            dz[p2] = spts[(long)idx * 3 + 2] - qpts[(nb + pp) * 3 + 2];
        }
#pragma unroll
        for (int p2 = 0; p2 < 2; p2++) {
            int pp = hf * 2 + p2;
            posd[w][pp][0][hh] = dx[p2];
            posd[w][pp][1][hh] = dy[p2];
            posd[w][pp][2][hh] = dz[p2];
        }
    }

    // ---- prologue C: feature gathers ----
    uint2 rj[4][8];
#pragma unroll
    for (int pp = 0; pp < 4; pp++)
#pragma unroll
        for (int j = 0; j < 8; j++)
            rj[pp][j] = *(const uint2*)(x1b + (long)idg[pp][j] * MIDF + 4 * dl);

#pragma unroll
    for (int pp = 0; pp < 4; pp++) {
        // A-frag: influences; vector LDS reads of posd
        union { float4 v; float f[4]; } px0, px1, py0, py1, pz0, pz1;
        px0.v = *(const float4*)&posd[w][pp][0][q4 * 8];
        px1.v = *(const float4*)&posd[w][pp][0][q4 * 8 + 4];
        py0.v = *(const float4*)&posd[w][pp][1][q4 * 8];
        py1.v = *(const float4*)&posd[w][pp][1][q4 * 8 + 4];
        pz0.v = *(const float4*)&posd[w][pp][2][q4 * 8];
        pz1.v = *(const float4*)&posd[w][pp][2][q4 * 8 + 4];

        float inf[8];
#pragma unroll
        for (int j = 0; j < 8; j++) {
            float ex = ((j < 4) ? px0.f[j & 3] : px1.f[j & 3]) - kx;
            float ey = ((j < 4) ? py0.f[j & 3] : py1.f[j & 3]) - ky;
            float ez = ((j < 4) ? pz0.f[j & 3] : pz1.f[j & 3]) - kz;
            float sq = ex * ex + ey * ey + ez * ez;
            float dist = sqrtf(fmaxf(sq, 1e-12f));
            inf[j] = fmaxf(0.f, 1.f - dist * (1.f / KPE));
        }
        // no dl<KP guard needed: wpk rows k=15 are zero, junk wf never contributes
        union { short8 v; unsigned d2[4]; } afr;
#pragma unroll
        for (int jj = 0; jj < 4; jj++)
            afr.d2[jj] = cvt_pk_bf16(inf[2 * jj], inf[2 * jj + 1]);

        // transpose 8 x (4 u16) -> 4 B-frags of 8 u16 via v_perm
        union { short8 v; unsigned d[4]; } bfr[4];
#pragma unroll
        for (int dj = 0; dj < 4; dj++) {
            unsigned a_lo = rj[pp][2 * dj].x, b_lo = rj[pp][2 * dj + 1].x;
            unsigned a_hi = rj[pp][2 * dj].y, b_hi = rj[pp][2 * dj + 1].y;
            bfr[0].d[dj] = __builtin_amdgcn_perm(b_lo, a_lo, 0x05040100u);
            bfr[1].d[dj] = __builtin_amdgcn_perm(b_lo, a_lo, 0x07060302u);
            bfr[2].d[dj] = __builtin_amdgcn_perm(b_hi, a_hi, 0x05040100u);
            bfr[3].d[dj] = __builtin_amdgcn_perm(b_hi, a_hi, 0x07060302u);
        }

        float4v wfa[4];
#pragma unroll
        for (int nt = 0; nt < 4; nt++)
            wfa[nt] = __builtin_amdgcn_mfma_f32_16x16x32_bf16(
                afr.v, bfr[nt].v, (float4v){0.f, 0.f, 0.f, 0.f}, 0, 0, 0);

        // wf write: wfs[p][d*16+k], d=nt*16+dl, k=q4*4+r; packed b64 via cvt_pk
        int p = w * 4 + pp;
#pragma unroll
        for (int nt = 0; nt < 4; nt++) {
            uint2 pk;
            pk.x = cvt_pk_bf16(wfa[nt][0], wfa[nt][1]);
            pk.y = cvt_pk_bf16(wfa[nt][2], wfa[nt][3]);
            *(uint2*)(&wfs[p][(nt * 16 + dl) * 16 + q4 * 4]) = pk;
        }
    }

    // issue first phase-3 B loads before the barrier (independent of wfs)
    const short8* Bq = (const short8*)kwp + l;
    short8 bc0 = Bq[(0 * 4 + w) * 64];
    short8 bc1 = Bq[(1 * 4 + w) * 64];
    __syncthreads();

    // phase 3: y[16][64] = wf[16][1024] @ wpk[1024][64]; wave w -> col tile w
    // two acc chains + explicit depth-2 B prefetch
    float4v acc0 = (float4v){0.f, 0.f, 0.f, 0.f};
    float4v acc1 = (float4v){0.f, 0.f, 0.f, 0.f};
    const ushort* arow = &wfs[dl][0] + q4 * 8;
#pragma unroll
    for (int s = 0; s < 32; s += 2) {
        short8 bn0, bn1;
        if (s < 30) {
            bn0 = Bq[((s + 2) * 4 + w) * 64];
            bn1 = Bq[((s + 3) * 4 + w) * 64];
        }
        short8 a0 = *(const short8*)(arow + s * 32);
        short8 a1 = *(const short8*)(arow + (s + 1) * 32);
        acc0 = __builtin_amdgcn_mfma_f32_16x16x32_bf16(a0, bc0, acc0, 0, 0, 0);
        acc1 = __builtin_amdgcn_mfma_f32_16x16x32_bf16(a1, bc1, acc1, 0, 0, 0);
        bc0 = bn0; bc1 = bn1;
    }
    float4v acc = acc0 + acc1;

    int o = w * 16 + dl;
    float s = 0.f, q = 0.f;
#pragma unroll
    for (int r = 0; r < 4; r++) {
        float v = acc[r];
        y[(long)(blockIdx.x * 16 + q4 * 4 + r) * MIDF + o] = f2bf(v);
        s += v; q += v * v;
    }
    s += __shfl_xor(s, 16); s += __shfl_xor(s, 32);
    q += __shfl_xor(q, 16); q += __shfl_xor(q, 32);
    if (q4 == 0) {
        atomicAdd(&Sa[o], s);
        atomicAdd(&Sq[o], q);
    }
}

// ---------- conv3 GEMM (BN2 inline on A), fused stats, x3b LINEAR ----------
__global__ __launch_bounds__(256)
void k_conv3(const ushort* __restrict__ x2raw, const ushort* __restrict__ Wp,
             ushort* __restrict__ x3b,
             const float* __restrict__ Sa2, const float* __restrict__ Sq2,
             const float* __restrict__ g2, const float* __restrict__ b2,
             float* __restrict__ Sa3, float* __restrict__ Sq3, int M) {
    __shared__ float sred[256], qred[256];
    __shared__ float scs[64], shs[64];
    int t = threadIdx.x;
    int w = t >> 6, l = t & 63;
    int dl = l & 15, q4 = l >> 4;

    if (t < 64) {
        float m = Sa2[t] * INVN;
        float v = Sq2[t] * INVN - m * m;
        float s = g2[t] * rsqrtf(v + EPSV);
        scs[t] = s; shs[t] = b2[t] - s * m;
    }
    sred[t] = 0.f; qred[t] = 0.f;
    __syncthreads();

    int m0 = blockIdx.x * 64 + w * 16;
    int row = m0 + dl;
    long arow = (row < M) ? row : (M - 1);
    const ushort* ap0 = x2raw + arow * MIDF + q4 * 8;
    short8 au2[2];
#pragma unroll
    for (int s = 0; s < 2; s++) {
        union { short8 v; ushort u[8]; } raw;
        union { short8 v; unsigned d[4]; } cv;
        raw.v = *(const short8*)(ap0 + s * 32);
        float fv[8];
#pragma unroll
        for (int e = 0; e < 8; e++) {
            int d = s * 32 + q4 * 8 + e;
            float f = bf2f(raw.u[e]) * scs[d] + shs[d];
            fv[e] = (f >= 0.f) ? f : SLOPE * f;
        }
#pragma unroll
        for (int e2 = 0; e2 < 4; e2++)
            cv.d[e2] = cvt_pk_bf16(fv[2 * e2], fv[2 * e2 + 1]);
        au2[s] = cv.v;
    }
    const short8* Bp = (const short8*)Wp + l;
    int rb = q4 * 4;
#pragma unroll
    for (int half = 0; half < 2; half++) {
        float4v acc[8];
#pragma unroll
        for (int j = 0; j < 8; j++) acc[j] = (float4v){0.f, 0.f, 0.f, 0.f};
#pragma unroll
        for (int s = 0; s < 2; s++)
#pragma unroll
            for (int j = 0; j < 8; j++) {
                short8 bf = Bp[(s * 16 + half * 8 + j) * 64];
                acc[j] = __builtin_amdgcn_mfma_f32_16x16x32_bf16(au2[s], bf, acc[j], 0, 0, 0);
            }
#pragma unroll
        for (int r = 0; r < 4; r++) {
            int rr = m0 + rb + r;
            if (rr < M) {
#pragma unroll
                for (int j = 0; j < 8; j++)
                    x3b[(long)rr * 256 + (half * 8 + j) * 16 + dl] = f2bf(acc[j][r]);
            }
        }
#pragma unroll
        for (int j = 0; j < 8; j++) {
            float s = 0.f, q = 0.f;
#pragma unroll
            for (int r = 0; r < 4; r++) {
                float v = ((m0 + rb + r) < M) ? acc[j][r] : 0.f;
                s += v; q += v * v;
            }
            s += __shfl_xor(s, 16); s += __shfl_xor(s, 32);
            q += __shfl_xor(q, 16); q += __shfl_xor(q, 32);
            if (q4 == 0) {
                atomicAdd(&sred[(half * 8 + j) * 16 + dl], s);
                atomicAdd(&qred[(half * 8 + j) * 16 + dl], q);
            }
        }
    }
    __syncthreads();
    atomicAdd(&Sa3[t], sred[t]);
    atomicAdd(&Sq3[t], qred[t]);
}

// ---------- final: inline finstats, lrelu(lrelu_bn(x3b) + lrelu_bn(scb)) -> f32 ----------
__global__ __launch_bounds__(256)
void k_final(const ushort* __restrict__ x3b, const ushort* __restrict__ scb,
             float* __restrict__ out,
             const float* __restrict__ a3, const float* __restrict__ q3,
             const float* __restrict__ g3, const float* __restrict__ b3,
             const float* __restrict__ aS, const float* __restrict__ qS,
             const float* __restrict__ gs, const float* __restrict__ bs) {
    __shared__ float s3[256], h3[256], sS[256], hS[256];
    int t = threadIdx.x;
    {
        float m = a3[t] * INVN;
        float v = q3[t] * INVN - m * m;
        float s = g3[t] * rsqrtf(v + EPSV);
        s3[t] = s; h3[t] = b3[t] - s * m;
        m = aS[t] * INVN;
        v = qS[t] * INVN - m * m;
        s = gs[t] * rsqrtf(v + EPSV);
        sS[t] = s; hS[t] = bs[t] - s * m;
    }
    __syncthreads();
    long i = (long)(blockIdx.x * 256 + t) * 4;
    int c0 = (int)(i & 255);
    ull va = *(const ull*)(x3b + i);
    ull vb = *(const ull*)(scb + i);
    float r[4];
#pragma unroll
    for (int j = 0; j < 4; j++) {
        int c = c0 + j;
        float x = bf2f((ushort)((va >> (16 * j)) & 0xffff)) * s3[c] + h3[c];
        x = (x >= 0.f) ? x : SLOPE * x;
        float sc = bf2f((ushort)((vb >> (16 * j)) & 0xffff)) * sS[c] + hS[c];
        sc = (sc >= 0.f) ? sc : SLOPE * sc;
        float v = x + sc;
        r[j] = (v >= 0.f) ? v : SLOPE * v;
    }
    *(float4*)(out + i) = (float4){r[0], r[1], r[2], r[3]};
}

extern "C" void kernel_launch(void* const* d_in, const int* in_sizes, int n_in,
                              void* d_out, int out_size, void* d_ws, size_t ws_size,
                              hipStream_t stream) {
    const float* qp   = (const float*)d_in[0];
    const float* sp   = (const float*)d_in[1];
    const int*   nbr  = (const int*)d_in[2];
    const float* feat = (const float*)d_in[3];
    const float* kpp  = (const float*)d_in[4];
    const float* w1   = (const float*)d_in[5];
    const float* g1   = (const float*)d_in[6];
    const float* b1   = (const float*)d_in[7];
    const float* kw   = (const float*)d_in[8];
    const float* g2   = (const float*)d_in[9];
    const float* b2   = (const float*)d_in[10];
    const float* w3   = (const float*)d_in[11];
    const float* g3   = (const float*)d_in[12];
    const float* b3   = (const float*)d_in[13];
    const float* wsw  = (const float*)d_in[14];
    const float* gs   = (const float*)d_in[15];
    const float* bs   = (const float*)d_in[16];
    float* out = (float*)d_out;

    char* base = (char*)d_ws;
    ushort* x1raw = (ushort*)(base + 0);          // 6.4 MB (permuted layout)
    ushort* x1b   = (ushort*)(base + 6400000);    // 6.4 MB (permuted layout)
    ushort* x2raw = (ushort*)(base + 12800000);   // 6.4 MB
    ushort* x3b   = (ushort*)(base + 19200000);   // 25.6 MB (linear)
    ushort* scb   = (ushort*)(base + 44800000);   // 25.6 MB (linear)
    ushort* wpC   = (ushort*)(base + 70400000);   // 80 KB
    ushort* wpk   = (ushort*)(base + 70481920);   // 128 KB (K=1024)
    ushort* wp3   = (ushort*)(base + 70612992);   // 32 KB
    float*  st    = (float*)(base + 70645760);
    float* acc1 = st,       *q1 = st + 64;
    float* acc2 = st + 128, *q2 = st + 192;
    float* acc3 = st + 256, *q3 = st + 512;
    float* accS = st + 768, *qS = st + 1024;

    hipMemsetAsync(st, 0, 1280 * sizeof(float), stream);

    k_repack_all<<<60, 256, 0, stream>>>(w1, wsw, wpC, kw, wpk, w3, wp3);

    // conv1 + shortcut fused (feat read once); x1 permuted, scb linear
    k_conv1sc<<<782, 256, 0, stream>>>(feat, wpC, x1raw, scb, acc1, q1, accS, qS, NPTS);
    k_bnx<<<3125, 256, 0, stream>>>(x1raw, x1b, acc1, q1, g1, b1);

    // KPConv: gather prefetch + MFMA, fused stats (r2-exact)
    k_kpconv<<<NPTS / 16, 256, 0, stream>>>(qp, sp, nbr, x1b, kpp, wpk, x2raw, acc2, q2);

    // conv3 with inline BN2+lrelu on A, fused stats, x3b linear
    k_conv3<<<782, 256, 0, stream>>>(x2raw, wp3, x3b, acc2, q2, g2, b2, acc3, q3, NPTS);

    // final combine (inline finstats; linear reads, contiguous float4 out)
    k_final<<<12500, 256, 0, stream>>>(x3b, scb, out, acc3, q3, g3, b3, accS, qS, gs, bs);
}

// Round 7
// 298.311 us; speedup vs baseline: 1.0029x; 1.0029x over previous
//
#include <hip/hip_runtime.h>

#define NPTS 50000
#define HN 32
#define INF1 128
#define OUTF3 256
#define MIDF 64
#define KP 15
#define EPSV 1e-6f
#define SLOPE 0.1f
#define KPE 0.48f   // 1.2 * 2.0 / 5.0
#define INVN (1.f / 50000.f)

typedef __attribute__((ext_vector_type(8))) short short8;   // 8 bf16
typedef __attribute__((ext_vector_type(4))) float float4v;  // MFMA acc
typedef unsigned short ushort;
typedef unsigned long long ull;

__device__ inline ushort f2bf(float f) {
    union { float f; unsigned u; } v; v.f = f;
    unsigned r = v.u + 0x7fff + ((v.u >> 16) & 1);
    return (ushort)(r >> 16);
}
__device__ inline float bf2f(ushort u) {
    union { unsigned u; float f; } v; v.u = ((unsigned)u) << 16;
    return v.f;
}
// pack 2 f32 -> 2 bf16 (RNE, bit-identical to f2bf) in ONE VALU instr
__device__ inline unsigned cvt_pk_bf16(float lo, float hi) {
    unsigned r;
    asm("v_cvt_pk_bf16_f32 %0, %1, %2" : "=v"(r) : "v"(lo), "v"(hi));
    return r;
}

// x1 rows are stored PERMUTED: mem offset m in [0,64) holds original feature
// d(m) = (m&3)*16 + (m>>2).  scb is LINEAR [n][256].
// k_kpconv / k_conv1sc / k_bnx / k_repack_all are the r5-passing versions,
// untouched.  NEW this round (replacing the r6 spin-barrier design that hung
// the GPU): x3b is eliminated via stats-then-recompute --
//   k_conv3stats : conv3 GEMM, stats only (no x3 store)
//   k_conv3final : recomputes the SAME GEMM (deterministic MFMA -> identical
//                  f32 accs), keeps x3 bf16 tile in LDS, applies the BN3 +
//                  shortcut epilogue with contiguous reads/stores.
// Stream ordering alone makes the stats complete before k_conv3final; no
// grid sync, no cooperative launch, no launch_bounds games.

// ---------- repack all weights f32 -> B-fragment bf16 ----------
__global__ __launch_bounds__(256)
void k_repack_all(const float* __restrict__ w1, const float* __restrict__ wsw,
                  ushort* __restrict__ wpC,
                  const float* __restrict__ kw, ushort* __restrict__ wpk,
                  const float* __restrict__ w3, ushort* __restrict__ wp3) {
    int id = blockIdx.x * 256 + threadIdx.x;
    if (id < 5120) {                      // wpC: [w1|wsw] K=128 N=320
        int l = id & 63;
        int nt = (id >> 6) % 20, s = id / 1280;
        int n = nt * 16 + (l & 15);
        int k0 = s * 32 + ((l >> 4) & 3) * 8;
#pragma unroll
        for (int j = 0; j < 8; j++) {
            float v = (n < 64) ? w1[(k0 + j) * 64 + n] : wsw[(k0 + j) * 256 + (n - 64)];
            wpC[id * 8 + j] = f2bf(v);
        }
    } else if (id < 13312) {              // wpk: kd = d*16+k (k=15 -> 0), K=1024 N=64
        int id2 = id - 5120;
        int l2 = id2 & 63;
        int nt = (id2 >> 6) & 3, s = id2 >> 8;
        int n = nt * 16 + (l2 & 15);
        int kd0 = s * 32 + ((l2 >> 4) & 3) * 8;
#pragma unroll
        for (int j = 0; j < 8; j++) {
            int kd = kd0 + j, d = kd >> 4, kk = kd & 15;
            float v = (kk < KP) ? kw[kk * 4096 + d * 64 + n] : 0.f;
            wpk[id2 * 8 + j] = f2bf(v);
        }
    } else if (id < 15360) {              // wp3: K=64 N=256
        int id3 = id - 13312;
        int l3 = id3 & 63;
        int nt = (id3 >> 6) % 16, s = id3 / 1024;
        int n = nt * 16 + (l3 & 15);
        int k0 = s * 32 + ((l3 >> 4) & 3) * 8;
#pragma unroll
        for (int j = 0; j < 8; j++)
            wp3[id3 * 8 + j] = f2bf(w3[(k0 + j) * 256 + n]);
    }
}

// ---------- conv1 + shortcut fused GEMM; x1 permuted, scb LINEAR ----------
__global__ __launch_bounds__(256)
void k_conv1sc(const float* __restrict__ feat, const ushort* __restrict__ WpC,
               ushort* __restrict__ x1raw, ushort* __restrict__ scb,
               float* __restrict__ Sa1, float* __restrict__ Sq1,
               float* __restrict__ SaS, float* __restrict__ SqS, int M) {
    __shared__ float sred[320], qred[320];
    int t = threadIdx.x;
    int w = t >> 6, l = t & 63;
    int dl = l & 15, q4 = l >> 4;

    for (int c = t; c < 320; c += 256) { sred[c] = 0.f; qred[c] = 0.f; }
    __syncthreads();

    int m0 = blockIdx.x * 64 + w * 16;
    int row = m0 + dl;
    long arow = (row < M) ? row : (M - 1);
    const float* ap0 = feat + arow * INF1 + q4 * 8;
    short8 afr[4];
#pragma unroll
    for (int s = 0; s < 4; s++) {
        float4 a0 = *(const float4*)(ap0 + s * 32);
        float4 a1 = *(const float4*)(ap0 + s * 32 + 4);
        union { short8 v; unsigned d[4]; } au;
        au.d[0] = cvt_pk_bf16(a0.x, a0.y);
        au.d[1] = cvt_pk_bf16(a0.z, a0.w);
        au.d[2] = cvt_pk_bf16(a1.x, a1.y);
        au.d[3] = cvt_pk_bf16(a1.z, a1.w);
        afr[s] = au.v;
    }
    const short8* Bp = (const short8*)WpC + l;
    int rb = q4 * 4;
#pragma unroll
    for (int half = 0; half < 2; half++) {
        float4v acc[10];
#pragma unroll
        for (int j = 0; j < 10; j++) acc[j] = (float4v){0.f, 0.f, 0.f, 0.f};
#pragma unroll
        for (int s = 0; s < 4; s++)
#pragma unroll
            for (int j = 0; j < 10; j++) {
                short8 bf = Bp[(s * 20 + half * 10 + j) * 64];
                acc[j] = __builtin_amdgcn_mfma_f32_16x16x32_bf16(afr[s], bf, acc[j], 0, 0, 0);
            }
#pragma unroll
        for (int r = 0; r < 4; r++) {
            int rr = m0 + rb + r;
            if (rr < M) {
                if (half == 0) {
                    // j=0..3 are x1 cols c=j*16+dl -> permuted offset 4*dl+j, packed b64
                    uint2 pk;
                    pk.x = cvt_pk_bf16(acc[0][r], acc[1][r]);
                    pk.y = cvt_pk_bf16(acc[2][r], acc[3][r]);
                    *(uint2*)(x1raw + (long)rr * 64 + 4 * dl) = pk;
#pragma unroll
                    for (int j = 4; j < 10; j++)
                        scb[(long)rr * 256 + (j * 16 + dl - 64)] = f2bf(acc[j][r]);
                } else {
#pragma unroll
                    for (int j = 0; j < 10; j++)
                        scb[(long)rr * 256 + ((10 + j) * 16 + dl - 64)] = f2bf(acc[j][r]);
                }
            }
        }
#pragma unroll
        for (int j = 0; j < 10; j++) {
            float s = 0.f, q = 0.f;
#pragma unroll
            for (int r = 0; r < 4; r++) {
                float v = ((m0 + rb + r) < M) ? acc[j][r] : 0.f;
                s += v; q += v * v;
            }
            s += __shfl_xor(s, 16); s += __shfl_xor(s, 32);
            q += __shfl_xor(q, 16); q += __shfl_xor(q, 32);
            if (q4 == 0) {
                atomicAdd(&sred[(half * 10 + j) * 16 + dl], s);
                atomicAdd(&qred[(half * 10 + j) * 16 + dl], q);
            }
        }
    }
    __syncthreads();
    for (int c = t; c < 320; c += 256) {
        if (c < 64) { atomicAdd(&Sa1[c], sred[c]); atomicAdd(&Sq1[c], qred[c]); }
        else        { atomicAdd(&SaS[c - 64], sred[c]); atomicAdd(&SqS[c - 64], qred[c]); }
    }
}

// ---------- BN1 + lrelu on permuted x1 (channel = d(m)) ----------
__global__ __launch_bounds__(256)
void k_bnx(const ushort* __restrict__ X, ushort* __restrict__ Y,
           const float* __restrict__ Sa, const float* __restrict__ Sq,
           const float* __restrict__ g, const float* __restrict__ b) {
    __shared__ float sc[64], sh[64];
    int t = threadIdx.x;
    if (t < 64) {
        float m = Sa[t] * INVN;
        float v = Sq[t] * INVN - m * m;
        float s = g[t] * rsqrtf(v + EPSV);
        sc[t] = s; sh[t] = b[t] - s * m;
    }
    __syncthreads();
    int i = blockIdx.x * 256 + t;
    long base = (long)i * 4;
    int dlp = i & 15;           // m0 = 4*dlp; element j has channel j*16+dlp
    ull vin = *(const ull*)(X + base);
    float vv[4];
#pragma unroll
    for (int j = 0; j < 4; j++) {
        int c = j * 16 + dlp;
        float f = bf2f((ushort)((vin >> (16 * j)) & 0xffff));
        float v = f * sc[c] + sh[c];
        vv[j] = (v >= 0.f) ? v : SLOPE * v;
    }
    uint2 vo;
    vo.x = cvt_pk_bf16(vv[0], vv[1]);
    vo.y = cvt_pk_bf16(vv[2], vv[3]);
    *(uint2*)(Y + base) = vo;
}

// ---------- fused KPConv (r5-exact, passing): gather prefetch + all-MFMA ----------
__global__ __launch_bounds__(256)
void k_kpconv(const float* __restrict__ qpts, const float* __restrict__ spts,
              const int* __restrict__ nbr, const ushort* __restrict__ x1b,
              const float* __restrict__ kpp, const ushort* __restrict__ kwp,
              ushort* __restrict__ y, float* __restrict__ Sa, float* __restrict__ Sq) {
    __shared__ __align__(16) ushort wfs[16][1032];  // [p][kd], kd=d*16+k, pitch 1032
    __shared__ float posd[4][4][3][HN];             // [wave][pp][comp][h]

    int t = threadIdx.x;
    int w = t >> 6, l = t & 63;
    int dl = l & 15, q4 = l >> 4;

    int kmin = (dl < KP) ? dl : (KP - 1);
    float kx = kpp[kmin * 3 + 0], ky = kpp[kmin * 3 + 1], kz = kpp[kmin * 3 + 2];

    int nb = blockIdx.x * 16 + w * 4;   // first point of this wave

    // ---- prologue A: per-lane gather-index loads for ALL 4 points ----
    int idg[4][8];
#pragma unroll
    for (int pp = 0; pp < 4; pp++) {
        const int4* np = (const int4*)(nbr + (long)(nb + pp) * HN + q4 * 8);
        int4 ia = np[0], ib = np[1];
        idg[pp][0] = ia.x; idg[pp][1] = ia.y; idg[pp][2] = ia.z; idg[pp][3] = ia.w;
        idg[pp][4] = ib.x; idg[pp][5] = ib.y; idg[pp][6] = ib.z; idg[pp][7] = ib.w;
    }

    // ---- prologue B: posd setup, both half-waves (hf=0 -> pp0,1; hf=1 -> pp2,3) ----
    {
        int hh = l & 31, hf = l >> 5;
        float dx[2], dy[2], dz[2];
#pragma unroll
        for (int p2 = 0; p2 < 2; p2++) {
            int pp = hf * 2 + p2;
            int idx = nbr[(long)(nb + pp) * HN + hh];
            dx[p2] = spts[(long)idx * 3 + 0] - qpts[(nb + pp) * 3 + 0];
            dy[p2] = spts[(long)idx * 3 + 1] - qpts[(nb + pp) * 3 + 1];
            dz[p2] = spts[(long)idx * 3 + 2] - qpts[(nb + pp) * 3 + 2];
        }
#pragma unroll
        for (int p2 = 0; p2 < 2; p2++) {
            int pp = hf * 2 + p2;
            posd[w][pp][0][hh] = dx[p2];
            posd[w][pp][1][hh] = dy[p2];
            posd[w][pp][2][hh] = dz[p2];
        }
    }

    // ---- prologue C: feature gathers ----
    uint2 rj[4][8];
#pragma unroll
    for (int pp = 0; pp < 4; pp++)
#pragma unroll
        for (int j = 0; j < 8; j++)
            rj[pp][j] = *(const uint2*)(x1b + (long)idg[pp][j] * MIDF + 4 * dl);

#pragma unroll
    for (int pp = 0; pp < 4; pp++) {
        // A-frag: influences; vector LDS reads of posd
        union { float4 v; float f[4]; } px0, px1, py0, py1, pz0, pz1;
        px0.v = *(const float4*)&posd[w][pp][0][q4 * 8];
        px1.v = *(const float4*)&posd[w][pp][0][q4 * 8 + 4];
        py0.v = *(const float4*)&posd[w][pp][1][q4 * 8];
        py1.v = *(const float4*)&posd[w][pp][1][q4 * 8 + 4];
        pz0.v = *(const float4*)&posd[w][pp][2][q4 * 8];
        pz1.v = *(const float4*)&posd[w][pp][2][q4 * 8 + 4];

        float inf[8];
#pragma unroll
        for (int j = 0; j < 8; j++) {
            float ex = ((j < 4) ? px0.f[j & 3] : px1.f[j & 3]) - kx;
            float ey = ((j < 4) ? py0.f[j & 3] : py1.f[j & 3]) - ky;
            float ez = ((j < 4) ? pz0.f[j & 3] : pz1.f[j & 3]) - kz;
            float sq = ex * ex + ey * ey + ez * ez;
            float dist = sqrtf(fmaxf(sq, 1e-12f));
            inf[j] = fmaxf(0.f, 1.f - dist * (1.f / KPE));
        }
        // no dl<KP guard needed: wpk rows k=15 are zero, junk wf never contributes
        union { short8 v; unsigned d2[4]; } afr;
#pragma unroll
        for (int jj = 0; jj < 4; jj++)
            afr.d2[jj] = cvt_pk_bf16(inf[2 * jj], inf[2 * jj + 1]);

        // transpose 8 x (4 u16) -> 4 B-frags of 8 u16 via v_perm
        union { short8 v; unsigned d[4]; } bfr[4];
#pragma unroll
        for (int dj = 0; dj < 4; dj++) {
            unsigned a_lo = rj[pp][2 * dj].x, b_lo = rj[pp][2 * dj + 1].x;
            unsigned a_hi = rj[pp][2 * dj].y, b_hi = rj[pp][2 * dj + 1].y;
            bfr[0].d[dj] = __builtin_amdgcn_perm(b_lo, a_lo, 0x05040100u);
            bfr[1].d[dj] = __builtin_amdgcn_perm(b_lo, a_lo, 0x07060302u);
            bfr[2].d[dj] = __builtin_amdgcn_perm(b_hi, a_hi, 0x05040100u);
            bfr[3].d[dj] = __builtin_amdgcn_perm(b_hi, a_hi, 0x07060302u);
        }

        float4v wfa[4];
#pragma unroll
        for (int nt = 0; nt < 4; nt++)
            wfa[nt] = __builtin_amdgcn_mfma_f32_16x16x32_bf16(
                afr.v, bfr[nt].v, (float4v){0.f, 0.f, 0.f, 0.f}, 0, 0, 0);

        // wf write: wfs[p][d*16+k], d=nt*16+dl, k=q4*4+r; packed b64 via cvt_pk
        int p = w * 4 + pp;
#pragma unroll
        for (int nt = 0; nt < 4; nt++) {
            uint2 pk;
            pk.x = cvt_pk_bf16(wfa[nt][0], wfa[nt][1]);
            pk.y = cvt_pk_bf16(wfa[nt][2], wfa[nt][3]);
            *(uint2*)(&wfs[p][(nt * 16 + dl) * 16 + q4 * 4]) = pk;
        }
    }

    // issue first phase-3 B loads before the barrier (independent of wfs)
    const short8* Bq = (const short8*)kwp + l;
    short8 bc0 = Bq[(0 * 4 + w) * 64];
    short8 bc1 = Bq[(1 * 4 + w) * 64];
    __syncthreads();

    // phase 3: y[16][64] = wf[16][1024] @ wpk[1024][64]; wave w -> col tile w
    // two acc chains + explicit depth-2 B prefetch
    float4v acc0 = (float4v){0.f, 0.f, 0.f, 0.f};
    float4v acc1 = (float4v){0.f, 0.f, 0.f, 0.f};
    const ushort* arow = &wfs[dl][0] + q4 * 8;
#pragma unroll
    for (int s = 0; s < 32; s += 2) {
        short8 bn0, bn1;
        if (s < 30) {
            bn0 = Bq[((s + 2) * 4 + w) * 64];
            bn1 = Bq[((s + 3) * 4 + w) * 64];
        }
        short8 a0 = *(const short8*)(arow + s * 32);
        short8 a1 = *(const short8*)(arow + (s + 1) * 32);
        acc0 = __builtin_amdgcn_mfma_f32_16x16x32_bf16(a0, bc0, acc0, 0, 0, 0);
        acc1 = __builtin_amdgcn_mfma_f32_16x16x32_bf16(a1, bc1, acc1, 0, 0, 0);
        bc0 = bn0; bc1 = bn1;
    }
    float4v acc = acc0 + acc1;

    int o = w * 16 + dl;
    float s = 0.f, q = 0.f;
#pragma unroll
    for (int r = 0; r < 4; r++) {
        float v = acc[r];
        y[(long)(blockIdx.x * 16 + q4 * 4 + r) * MIDF + o] = f2bf(v);
        s += v; q += v * v;
    }
    s += __shfl_xor(s, 16); s += __shfl_xor(s, 32);
    q += __shfl_xor(q, 16); q += __shfl_xor(q, 32);
    if (q4 == 0) {
        atomicAdd(&Sa[o], s);
        atomicAdd(&Sq[o], q);
    }
}

// ---------- conv3 stats only: GEMM (BN2 inline on A), stats, NO x3 store ----------
__global__ __launch_bounds__(256)
void k_conv3stats(const ushort* __restrict__ x2raw, const ushort* __restrict__ Wp,
                  const float* __restrict__ Sa2, const float* __restrict__ Sq2,
                  const float* __restrict__ g2, const float* __restrict__ b2,
                  float* __restrict__ Sa3, float* __restrict__ Sq3, int M) {
    __shared__ float sred[256], qred[256];
    __shared__ float scs[64], shs[64];
    int t = threadIdx.x;
    int w = t >> 6, l = t & 63;
    int dl = l & 15, q4 = l >> 4;

    if (t < 64) {
        float m = Sa2[t] * INVN;
        float v = Sq2[t] * INVN - m * m;
        float s = g2[t] * rsqrtf(v + EPSV);
        scs[t] = s; shs[t] = b2[t] - s * m;
    }
    sred[t] = 0.f; qred[t] = 0.f;
    __syncthreads();

    int m0 = blockIdx.x * 64 + w * 16;
    int row = m0 + dl;
    long arow = (row < M) ? row : (M - 1);
    const ushort* ap0 = x2raw + arow * MIDF + q4 * 8;
    short8 au2[2];
#pragma unroll
    for (int s = 0; s < 2; s++) {
        union { short8 v; ushort u[8]; } raw;
        union { short8 v; unsigned d[4]; } cv;
        raw.v = *(const short8*)(ap0 + s * 32);
        float fv[8];
#pragma unroll
        for (int e = 0; e < 8; e++) {
            int d = s * 32 + q4 * 8 + e;
            float f = bf2f(raw.u[e]) * scs[d] + shs[d];
            fv[e] = (f >= 0.f) ? f : SLOPE * f;
        }
#pragma unroll
        for (int e2 = 0; e2 < 4; e2++)
            cv.d[e2] = cvt_pk_bf16(fv[2 * e2], fv[2 * e2 + 1]);
        au2[s] = cv.v;
    }
    const short8* Bp = (const short8*)Wp + l;
    int rb = q4 * 4;
#pragma unroll
    for (int half = 0; half < 2; half++) {
        float4v acc[8];
#pragma unroll
        for (int j = 0; j < 8; j++) acc[j] = (float4v){0.f, 0.f, 0.f, 0.f};
#pragma unroll
        for (int s = 0; s < 2; s++)
#pragma unroll
            for (int j = 0; j < 8; j++) {
                short8 bf = Bp[(s * 16 + half * 8 + j) * 64];
                acc[j] = __builtin_amdgcn_mfma_f32_16x16x32_bf16(au2[s], bf, acc[j], 0, 0, 0);
            }
#pragma unroll
        for (int j = 0; j < 8; j++) {
            float s = 0.f, q = 0.f;
#pragma unroll
            for (int r = 0; r < 4; r++) {
                float v = ((m0 + rb + r) < M) ? acc[j][r] : 0.f;
                s += v; q += v * v;
            }
            s += __shfl_xor(s, 16); s += __shfl_xor(s, 32);
            q += __shfl_xor(q, 16); q += __shfl_xor(q, 32);
            if (q4 == 0) {
                atomicAdd(&sred[(half * 8 + j) * 16 + dl], s);
                atomicAdd(&qred[(half * 8 + j) * 16 + dl], q);
            }
        }
    }
    __syncthreads();
    atomicAdd(&Sa3[t], sred[t]);
    atomicAdd(&Sq3[t], qred[t]);
}

// ---------- conv3 recompute + final epilogue: x3 tile in LDS, no global x3 ----------
__global__ __launch_bounds__(256)
void k_conv3final(const ushort* __restrict__ x2raw, const ushort* __restrict__ Wp,
                  const ushort* __restrict__ scb, float* __restrict__ out,
                  const float* __restrict__ Sa2, const float* __restrict__ Sq2,
                  const float* __restrict__ g2, const float* __restrict__ b2,
                  const float* __restrict__ a3, const float* __restrict__ q3,
                  const float* __restrict__ g3, const float* __restrict__ b3,
                  const float* __restrict__ aS, const float* __restrict__ qS,
                  const float* __restrict__ gs, const float* __restrict__ bs,
                  int M) {
    __shared__ float scs[64], shs[64];
    __shared__ float s3[256], h3[256], sS[256], hS[256];
    __shared__ __align__(8) ushort x3t[64][256];   // 32 KB bf16 strip
    int t = threadIdx.x;
    int w = t >> 6, l = t & 63;
    int dl = l & 15, q4 = l >> 4;

    if (t < 64) {
        float m = Sa2[t] * INVN;
        float v = Sq2[t] * INVN - m * m;
        float s = g2[t] * rsqrtf(v + EPSV);
        scs[t] = s; shs[t] = b2[t] - s * m;
    }
    {   // BN3 + BN-shortcut coefficients (stats complete: prior kernels on stream)
        float m = a3[t] * INVN;
        float v = q3[t] * INVN - m * m;
        float s = g3[t] * rsqrtf(v + EPSV);
        s3[t] = s; h3[t] = b3[t] - s * m;
        m = aS[t] * INVN;
        v = qS[t] * INVN - m * m;
        s = gs[t] * rsqrtf(v + EPSV);
        sS[t] = s; hS[t] = bs[t] - s * m;
    }
    __syncthreads();

    // ---- phase A: conv3 GEMM recompute (identical accs to k_conv3stats),
    //      x3 bf16 (same f2bf rounding as the old global x3b path) -> LDS ----
    int m0 = blockIdx.x * 64 + w * 16;
    int row = m0 + dl;
    long arow = (row < M) ? row : (M - 1);
    const ushort* ap0 = x2raw + arow * MIDF + q4 * 8;
    short8 au2[2];
#pragma unroll
    for (int s = 0; s < 2; s++) {
        union { short8 v; ushort u[8]; } raw;
        union { short8 v; unsigned d[4]; } cv;
        raw.v = *(const short8*)(ap0 + s * 32);
        float fv[8];
#pragma unroll
        for (int e = 0; e < 8; e++) {
            int d = s * 32 + q4 * 8 + e;
            float f = bf2f(raw.u[e]) * scs[d] + shs[d];
            fv[e] = (f >= 0.f) ? f : SLOPE * f;
        }
#pragma unroll
        for (int e2 = 0; e2 < 4; e2++)
            cv.d[e2] = cvt_pk_bf16(fv[2 * e2], fv[2 * e2 + 1]);
        au2[s] = cv.v;
    }
    const short8* Bp = (const short8*)Wp + l;
    int rb = q4 * 4;
#pragma unroll
    for (int half = 0; half < 2; half++) {
        float4v acc[8];
#pragma unroll
        for (int j = 0; j < 8; j++) acc[j] = (float4v){0.f, 0.f, 0.f, 0.f};
#pragma unroll
        for (int s = 0; s < 2; s++)
#pragma unroll
            for (int j = 0; j < 8; j++) {
                short8 bf = Bp[(s * 16 + half * 8 + j) * 64];
                acc[j] = __builtin_amdgcn_mfma_f32_16x16x32_bf16(au2[s], bf, acc[j], 0, 0, 0);
            }
#pragma unroll
        for (int r = 0; r < 4; r++) {
            int lrow = w * 16 + rb + r;
#pragma unroll
            for (int j = 0; j < 8; j++)
                x3t[lrow][(half * 8 + j) * 16 + dl] = f2bf(acc[j][r]);
        }
    }
    __syncthreads();

    // ---- phase B: epilogue; x3 from LDS, scb/out contiguous ----
#pragma unroll
    for (int it = 0; it < 16; it++) {
        int e = it * 1024 + t * 4;          // 0..16383 over [64][256]
        int lrow = e >> 8;
        int grow = blockIdx.x * 64 + lrow;
        if (grow < M) {
            int col = e & 255;
            ull va = *(const ull*)&x3t[lrow][col];
            ull vb = *(const ull*)(scb + (long)grow * 256 + col);
            float r[4];
#pragma unroll
            for (int j = 0; j < 4; j++) {
                int c = col + j;
                float x = bf2f((ushort)((va >> (16 * j)) & 0xffff)) * s3[c] + h3[c];
                x = (x >= 0.f) ? x : SLOPE * x;
                float sc = bf2f((ushort)((vb >> (16 * j)) & 0xffff)) * sS[c] + hS[c];
                sc = (sc >= 0.f) ? sc : SLOPE * sc;
                float v = x + sc;
                r[j] = (v >= 0.f) ? v : SLOPE * v;
            }
            *(float4*)(out + (long)grow * 256 + col) = (float4){r[0], r[1], r[2], r[3]};
        }
    }
}

extern "C" void kernel_launch(void* const* d_in, const int* in_sizes, int n_in,
                              void* d_out, int out_size, void* d_ws, size_t ws_size,
                              hipStream_t stream) {
    const float* qp   = (const float*)d_in[0];
    const float* sp   = (const float*)d_in[1];
    const int*   nbr  = (const int*)d_in[2];
    const float* feat = (const float*)d_in[3];
    const float* kpp  = (const float*)d_in[4];
    const float* w1   = (const float*)d_in[5];
    const float* g1   = (const float*)d_in[6];
    const float* b1   = (const float*)d_in[7];
    const float* kw   = (const float*)d_in[8];
    const float* g2   = (const float*)d_in[9];
    const float* b2   = (const float*)d_in[10];
    const float* w3   = (const float*)d_in[11];
    const float* g3   = (const float*)d_in[12];
    const float* b3   = (const float*)d_in[13];
    const float* wsw  = (const float*)d_in[14];
    const float* gs   = (const float*)d_in[15];
    const float* bs   = (const float*)d_in[16];
    float* out = (float*)d_out;

    char* base = (char*)d_ws;
    ushort* x1raw = (ushort*)(base + 0);          // 6.4 MB (permuted layout)
    ushort* x1b   = (ushort*)(base + 6400000);    // 6.4 MB (permuted layout)
    ushort* x2raw = (ushort*)(base + 12800000);   // 6.4 MB
    ushort* scb   = (ushort*)(base + 44800000);   // 25.6 MB (linear)
    ushort* wpC   = (ushort*)(base + 70400000);   // 80 KB
    ushort* wpk   = (ushort*)(base + 70481920);   // 128 KB (K=1024)
    ushort* wp3   = (ushort*)(base + 70612992);   // 32 KB
    float*  st    = (float*)(base + 70645760);
    float* acc1 = st,       *q1 = st + 64;
    float* acc2 = st + 128, *q2 = st + 192;
    float* acc3 = st + 256, *q3 = st + 512;
    float* accS = st + 768, *qS = st + 1024;

    hipMemsetAsync(st, 0, 1280 * sizeof(float), stream);

    k_repack_all<<<60, 256, 0, stream>>>(w1, wsw, wpC, kw, wpk, w3, wp3);

    // conv1 + shortcut fused (feat read once); x1 permuted, scb linear
    k_conv1sc<<<782, 256, 0, stream>>>(feat, wpC, x1raw, scb, acc1, q1, accS, qS, NPTS);
    k_bnx<<<3125, 256, 0, stream>>>(x1raw, x1b, acc1, q1, g1, b1);

    // KPConv: gather prefetch + MFMA, fused stats (r5-exact)
    k_kpconv<<<NPTS / 16, 256, 0, stream>>>(qp, sp, nbr, x1b, kpp, wpk, x2raw, acc2, q2);

    // conv3 stats pass (no x3 store), then recompute + fused final epilogue
    k_conv3stats<<<782, 256, 0, stream>>>(x2raw, wp3, acc2, q2, g2, b2, acc3, q3, NPTS);
    k_conv3final<<<782, 256, 0, stream>>>(x2raw, wp3, scb, out,
                                          acc2, q2, g2, b2, acc3, q3,
                                          g3, b3, accS, qS, gs, bs, NPTS);
}

// Round 8
// 295.650 us; speedup vs baseline: 1.0120x; 1.0090x over previous
//
#include <hip/hip_runtime.h>

#define NPTS 50000
#define HN 32
#define INF1 128
#define OUTF3 256
#define MIDF 64
#define KP 15
#define EPSV 1e-6f
#define SLOPE 0.1f
#define KPE 0.48f   // 1.2 * 2.0 / 5.0
#define INVN (1.f / 50000.f)

typedef __attribute__((ext_vector_type(8))) short short8;   // 8 bf16
typedef __attribute__((ext_vector_type(4))) float float4v;  // MFMA acc
typedef unsigned short ushort;
typedef unsigned long long ull;

__device__ inline ushort f2bf(float f) {
    union { float f; unsigned u; } v; v.f = f;
    unsigned r = v.u + 0x7fff + ((v.u >> 16) & 1);
    return (ushort)(r >> 16);
}
__device__ inline float bf2f(ushort u) {
    union { unsigned u; float f; } v; v.u = ((unsigned)u) << 16;
    return v.f;
}
__device__ inline float u2f(unsigned u) {          // bits -> float
    union { unsigned u; float f; } v; v.u = u; return v.f;
}
// pack 2 f32 -> 2 bf16 (RNE, bit-identical to f2bf) in ONE VALU instr
__device__ inline unsigned cvt_pk_bf16(float lo, float hi) {
    unsigned r;
    asm("v_cvt_pk_bf16_f32 %0, %1, %2" : "=v"(r) : "v"(lo), "v"(hi));
    return r;
}

// x1 rows are stored PERMUTED: mem offset m in [0,64) holds original feature
// d(m) = (m&3)*16 + (m>>2).  scb is LINEAR [n][256].
// THIS ROUND (vs r7, both numerics-identical fusions):
//  - k_bnx DELETED: BN1+lrelu fused into k_kpconv's gather path.  kpconv
//    gathers pre-BN x1raw; each gathered b64 holds channels {dl,16+dl,
//    32+dl,48+dl} (lane-deterministic), so 4 scale/shift pairs live in
//    registers.  unpack->fma->lrelu->cvt_pk replicates bnx op-for-op =>
//    bit-identical bf16 into the MFMA.
//  - stats memset folded into k_repack_all (block 60).
//  7 dispatches -> 5.  conv1sc/conv3stats/conv3final are r7-exact.

// ---------- repack all weights f32 -> B-fragment bf16 (+ stats zeroing) ----------
__global__ __launch_bounds__(256)
void k_repack_all(const float* __restrict__ w1, const float* __restrict__ wsw,
                  ushort* __restrict__ wpC,
                  const float* __restrict__ kw, ushort* __restrict__ wpk,
                  const float* __restrict__ w3, ushort* __restrict__ wp3,
                  float* __restrict__ st) {
    int id = blockIdx.x * 256 + threadIdx.x;
    if (id < 5120) {                      // wpC: [w1|wsw] K=128 N=320
        int l = id & 63;
        int nt = (id >> 6) % 20, s = id / 1280;
        int n = nt * 16 + (l & 15);
        int k0 = s * 32 + ((l >> 4) & 3) * 8;
#pragma unroll
        for (int j = 0; j < 8; j++) {
            float v = (n < 64) ? w1[(k0 + j) * 64 + n] : wsw[(k0 + j) * 256 + (n - 64)];
            wpC[id * 8 + j] = f2bf(v);
        }
    } else if (id < 13312) {              // wpk: kd = d*16+k (k=15 -> 0), K=1024 N=64
        int id2 = id - 5120;
        int l2 = id2 & 63;
        int nt = (id2 >> 6) & 3, s = id2 >> 8;
        int n = nt * 16 + (l2 & 15);
        int kd0 = s * 32 + ((l2 >> 4) & 3) * 8;
#pragma unroll
        for (int j = 0; j < 8; j++) {
            int kd = kd0 + j, d = kd >> 4, kk = kd & 15;
            float v = (kk < KP) ? kw[kk * 4096 + d * 64 + n] : 0.f;
            wpk[id2 * 8 + j] = f2bf(v);
        }
    } else if (id < 15360) {              // wp3: K=64 N=256
        int id3 = id - 13312;
        int l3 = id3 & 63;
        int nt = (id3 >> 6) % 16, s = id3 / 1024;
        int n = nt * 16 + (l3 & 15);
        int k0 = s * 32 + ((l3 >> 4) & 3) * 8;
#pragma unroll
        for (int j = 0; j < 8; j++)
            wp3[id3 * 8 + j] = f2bf(w3[(k0 + j) * 256 + n]);
    } else {                              // block 60: zero the stats block
        int c = id - 15360;
        for (int k = c; k < 1280; k += 256) st[k] = 0.f;
    }
}

// ---------- conv1 + shortcut fused GEMM; x1 permuted, scb LINEAR ----------
__global__ __launch_bounds__(256)
void k_conv1sc(const float* __restrict__ feat, const ushort* __restrict__ WpC,
               ushort* __restrict__ x1raw, ushort* __restrict__ scb,
               float* __restrict__ Sa1, float* __restrict__ Sq1,
               float* __restrict__ SaS, float* __restrict__ SqS, int M) {
    __shared__ float sred[320], qred[320];
    int t = threadIdx.x;
    int w = t >> 6, l = t & 63;
    int dl = l & 15, q4 = l >> 4;

    for (int c = t; c < 320; c += 256) { sred[c] = 0.f; qred[c] = 0.f; }
    __syncthreads();

    int m0 = blockIdx.x * 64 + w * 16;
    int row = m0 + dl;
    long arow = (row < M) ? row : (M - 1);
    const float* ap0 = feat + arow * INF1 + q4 * 8;
    short8 afr[4];
#pragma unroll
    for (int s = 0; s < 4; s++) {
        float4 a0 = *(const float4*)(ap0 + s * 32);
        float4 a1 = *(const float4*)(ap0 + s * 32 + 4);
        union { short8 v; unsigned d[4]; } au;
        au.d[0] = cvt_pk_bf16(a0.x, a0.y);
        au.d[1] = cvt_pk_bf16(a0.z, a0.w);
        au.d[2] = cvt_pk_bf16(a1.x, a1.y);
        au.d[3] = cvt_pk_bf16(a1.z, a1.w);
        afr[s] = au.v;
    }
    const short8* Bp = (const short8*)WpC + l;
    int rb = q4 * 4;
#pragma unroll
    for (int half = 0; half < 2; half++) {
        float4v acc[10];
#pragma unroll
        for (int j = 0; j < 10; j++) acc[j] = (float4v){0.f, 0.f, 0.f, 0.f};
#pragma unroll
        for (int s = 0; s < 4; s++)
#pragma unroll
            for (int j = 0; j < 10; j++) {
                short8 bf = Bp[(s * 20 + half * 10 + j) * 64];
                acc[j] = __builtin_amdgcn_mfma_f32_16x16x32_bf16(afr[s], bf, acc[j], 0, 0, 0);
            }
#pragma unroll
        for (int r = 0; r < 4; r++) {
            int rr = m0 + rb + r;
            if (rr < M) {
                if (half == 0) {
                    // j=0..3 are x1 cols c=j*16+dl -> permuted offset 4*dl+j, packed b64
                    uint2 pk;
                    pk.x = cvt_pk_bf16(acc[0][r], acc[1][r]);
                    pk.y = cvt_pk_bf16(acc[2][r], acc[3][r]);
                    *(uint2*)(x1raw + (long)rr * 64 + 4 * dl) = pk;
#pragma unroll
                    for (int j = 4; j < 10; j++)
                        scb[(long)rr * 256 + (j * 16 + dl - 64)] = f2bf(acc[j][r]);
                } else {
#pragma unroll
                    for (int j = 0; j < 10; j++)
                        scb[(long)rr * 256 + ((10 + j) * 16 + dl - 64)] = f2bf(acc[j][r]);
                }
            }
        }
#pragma unroll
        for (int j = 0; j < 10; j++) {
            float s = 0.f, q = 0.f;
#pragma unroll
            for (int r = 0; r < 4; r++) {
                float v = ((m0 + rb + r) < M) ? acc[j][r] : 0.f;
                s += v; q += v * v;
            }
            s += __shfl_xor(s, 16); s += __shfl_xor(s, 32);
            q += __shfl_xor(q, 16); q += __shfl_xor(q, 32);
            if (q4 == 0) {
                atomicAdd(&sred[(half * 10 + j) * 16 + dl], s);
                atomicAdd(&qred[(half * 10 + j) * 16 + dl], q);
            }
        }
    }
    __syncthreads();
    for (int c = t; c < 320; c += 256) {
        if (c < 64) { atomicAdd(&Sa1[c], sred[c]); atomicAdd(&Sq1[c], qred[c]); }
        else        { atomicAdd(&SaS[c - 64], sred[c]); atomicAdd(&SqS[c - 64], qred[c]); }
    }
}

// ---------- fused KPConv: BN1+lrelu applied post-gather (bnx folded in) ----------
__global__ __launch_bounds__(256)
void k_kpconv(const float* __restrict__ qpts, const float* __restrict__ spts,
              const int* __restrict__ nbr, const ushort* __restrict__ x1raw,
              const float* __restrict__ kpp, const ushort* __restrict__ kwp,
              ushort* __restrict__ y, float* __restrict__ Sa, float* __restrict__ Sq,
              const float* __restrict__ Sa1, const float* __restrict__ Sq1,
              const float* __restrict__ g1, const float* __restrict__ b1) {
    __shared__ __align__(16) ushort wfs[16][1032];  // [p][kd], kd=d*16+k, pitch 1032
    __shared__ float posd[4][4][3][HN];             // [wave][pp][comp][h]
    __shared__ float sc1[64], sh1[64];

    int t = threadIdx.x;
    int w = t >> 6, l = t & 63;
    int dl = l & 15, q4 = l >> 4;

    // BN1 coefficients (same formula as the old k_bnx)
    if (t < 64) {
        float m = Sa1[t] * INVN;
        float v = Sq1[t] * INVN - m * m;
        float s = g1[t] * rsqrtf(v + EPSV);
        sc1[t] = s; sh1[t] = b1[t] - s * m;
    }
    __syncthreads();
    // per-lane coeffs for the 4 channels in this lane's gathered b64: c=j*16+dl
    float scl[4], shl[4];
#pragma unroll
    for (int j = 0; j < 4; j++) { scl[j] = sc1[j * 16 + dl]; shl[j] = sh1[j * 16 + dl]; }

    int kmin = (dl < KP) ? dl : (KP - 1);
    float kx = kpp[kmin * 3 + 0], ky = kpp[kmin * 3 + 1], kz = kpp[kmin * 3 + 2];

    int nb = blockIdx.x * 16 + w * 4;   // first point of this wave

    // ---- prologue A: per-lane gather-index loads for ALL 4 points ----
    int idg[4][8];
#pragma unroll
    for (int pp = 0; pp < 4; pp++) {
        const int4* np = (const int4*)(nbr + (long)(nb + pp) * HN + q4 * 8);
        int4 ia = np[0], ib = np[1];
        idg[pp][0] = ia.x; idg[pp][1] = ia.y; idg[pp][2] = ia.z; idg[pp][3] = ia.w;
        idg[pp][4] = ib.x; idg[pp][5] = ib.y; idg[pp][6] = ib.z; idg[pp][7] = ib.w;
    }

    // ---- prologue B: posd setup, both half-waves (hf=0 -> pp0,1; hf=1 -> pp2,3) ----
    {
        int hh = l & 31, hf = l >> 5;
        float dx[2], dy[2], dz[2];
#pragma unroll
        for (int p2 = 0; p2 < 2; p2++) {
            int pp = hf * 2 + p2;
            int idx = nbr[(long)(nb + pp) * HN + hh];
            dx[p2] = spts[(long)idx * 3 + 0] - qpts[(nb + pp) * 3 + 0];
            dy[p2] = spts[(long)idx * 3 + 1] - qpts[(nb + pp) * 3 + 1];
            dz[p2] = spts[(long)idx * 3 + 2] - qpts[(nb + pp) * 3 + 2];
        }
#pragma unroll
        for (int p2 = 0; p2 < 2; p2++) {
            int pp = hf * 2 + p2;
            posd[w][pp][0][hh] = dx[p2];
            posd[w][pp][1][hh] = dy[p2];
            posd[w][pp][2][hh] = dz[p2];
        }
    }

    // ---- prologue C: feature gathers (pre-BN x1raw) ----
    uint2 rj[4][8];
#pragma unroll
    for (int pp = 0; pp < 4; pp++)
#pragma unroll
        for (int j = 0; j < 8; j++)
            rj[pp][j] = *(const uint2*)(x1raw + (long)idg[pp][j] * MIDF + 4 * dl);

#pragma unroll
    for (int pp = 0; pp < 4; pp++) {
        // A-frag: influences; vector LDS reads of posd
        union { float4 v; float f[4]; } px0, px1, py0, py1, pz0, pz1;
        px0.v = *(const float4*)&posd[w][pp][0][q4 * 8];
        px1.v = *(const float4*)&posd[w][pp][0][q4 * 8 + 4];
        py0.v = *(const float4*)&posd[w][pp][1][q4 * 8];
        py1.v = *(const float4*)&posd[w][pp][1][q4 * 8 + 4];
        pz0.v = *(const float4*)&posd[w][pp][2][q4 * 8];
        pz1.v = *(const float4*)&posd[w][pp][2][q4 * 8 + 4];

        float inf[8];
#pragma unroll
        for (int j = 0; j < 8; j++) {
            float ex = ((j < 4) ? px0.f[j & 3] : px1.f[j & 3]) - kx;
            float ey = ((j < 4) ? py0.f[j & 3] : py1.f[j & 3]) - ky;
            float ez = ((j < 4) ? pz0.f[j & 3] : pz1.f[j & 3]) - kz;
            float sq = ex * ex + ey * ey + ez * ez;
            float dist = sqrtf(fmaxf(sq, 1e-12f));
            inf[j] = fmaxf(0.f, 1.f - dist * (1.f / KPE));
        }
        // no dl<KP guard needed: wpk rows k=15 are zero, junk wf never contributes
        union { short8 v; unsigned d2[4]; } afr;
#pragma unroll
        for (int jj = 0; jj < 4; jj++)
            afr.d2[jj] = cvt_pk_bf16(inf[2 * jj], inf[2 * jj + 1]);

        // BN1 + lrelu on each gathered b64 (op-identical to old k_bnx),
        // then transpose 8 x (4 u16) -> 4 B-frags of 8 u16 via v_perm
        uint2 rb8[8];
#pragma unroll
        for (int j = 0; j < 8; j++) {
            unsigned lo = rj[pp][j].x, hi = rj[pp][j].y;
            float v0 = u2f(lo << 16)          * scl[0] + shl[0];
            float v1 = u2f(lo & 0xffff0000u)  * scl[1] + shl[1];
            float v2 = u2f(hi << 16)          * scl[2] + shl[2];
            float v3 = u2f(hi & 0xffff0000u)  * scl[3] + shl[3];
            v0 = (v0 >= 0.f) ? v0 : SLOPE * v0;
            v1 = (v1 >= 0.f) ? v1 : SLOPE * v1;
            v2 = (v2 >= 0.f) ? v2 : SLOPE * v2;
            v3 = (v3 >= 0.f) ? v3 : SLOPE * v3;
            rb8[j].x = cvt_pk_bf16(v0, v1);
            rb8[j].y = cvt_pk_bf16(v2, v3);
        }
        union { short8 v; unsigned d[4]; } bfr[4];
#pragma unroll
        for (int dj = 0; dj < 4; dj++) {
            unsigned a_lo = rb8[2 * dj].x, b_lo = rb8[2 * dj + 1].x;
            unsigned a_hi = rb8[2 * dj].y, b_hi = rb8[2 * dj + 1].y;
            bfr[0].d[dj] = __builtin_amdgcn_perm(b_lo, a_lo, 0x05040100u);
            bfr[1].d[dj] = __builtin_amdgcn_perm(b_lo, a_lo, 0x07060302u);
            bfr[2].d[dj] = __builtin_amdgcn_perm(b_hi, a_hi, 0x05040100u);
            bfr[3].d[dj] = __builtin_amdgcn_perm(b_hi, a_hi, 0x07060302u);
        }

        float4v wfa[4];
#pragma unroll
        for (int nt = 0; nt < 4; nt++)
            wfa[nt] = __builtin_amdgcn_mfma_f32_16x16x32_bf16(
                afr.v, bfr[nt].v, (float4v){0.f, 0.f, 0.f, 0.f}, 0, 0, 0);

        // wf write: wfs[p][d*16+k], d=nt*16+dl, k=q4*4+r; packed b64 via cvt_pk
        int p = w * 4 + pp;
#pragma unroll
        for (int nt = 0; nt < 4; nt++) {
            uint2 pk;
            pk.x = cvt_pk_bf16(wfa[nt][0], wfa[nt][1]);
            pk.y = cvt_pk_bf16(wfa[nt][2], wfa[nt][3]);
            *(uint2*)(&wfs[p][(nt * 16 + dl) * 16 + q4 * 4]) = pk;
        }
    }

    // issue first phase-3 B loads before the barrier (independent of wfs)
    const short8* Bq = (const short8*)kwp + l;
    short8 bc0 = Bq[(0 * 4 + w) * 64];
    short8 bc1 = Bq[(1 * 4 + w) * 64];
    __syncthreads();

    // phase 3: y[16][64] = wf[16][1024] @ wpk[1024][64]; wave w -> col tile w
    // two acc chains + explicit depth-2 B prefetch
    float4v acc0 = (float4v){0.f, 0.f, 0.f, 0.f};
    float4v acc1 = (float4v){0.f, 0.f, 0.f, 0.f};
    const ushort* arow = &wfs[dl][0] + q4 * 8;
#pragma unroll
    for (int s = 0; s < 32; s += 2) {
        short8 bn0, bn1;
        if (s < 30) {
            bn0 = Bq[((s + 2) * 4 + w) * 64];
            bn1 = Bq[((s + 3) * 4 + w) * 64];
        }
        short8 a0 = *(const short8*)(arow + s * 32);
        short8 a1 = *(const short8*)(arow + (s + 1) * 32);
        acc0 = __builtin_amdgcn_mfma_f32_16x16x32_bf16(a0, bc0, acc0, 0, 0, 0);
        acc1 = __builtin_amdgcn_mfma_f32_16x16x32_bf16(a1, bc1, acc1, 0, 0, 0);
        bc0 = bn0; bc1 = bn1;
    }
    float4v acc = acc0 + acc1;

    int o = w * 16 + dl;
    float s = 0.f, q = 0.f;
#pragma unroll
    for (int r = 0; r < 4; r++) {
        float v = acc[r];
        y[(long)(blockIdx.x * 16 + q4 * 4 + r) * MIDF + o] = f2bf(v);
        s += v; q += v * v;
    }
    s += __shfl_xor(s, 16); s += __shfl_xor(s, 32);
    q += __shfl_xor(q, 16); q += __shfl_xor(q, 32);
    if (q4 == 0) {
        atomicAdd(&Sa[o], s);
        atomicAdd(&Sq[o], q);
    }
}

// ---------- conv3 stats only: GEMM (BN2 inline on A), stats, NO x3 store ----------
__global__ __launch_bounds__(256)
void k_conv3stats(const ushort* __restrict__ x2raw, const ushort* __restrict__ Wp,
                  const float* __restrict__ Sa2, const float* __restrict__ Sq2,
                  const float* __restrict__ g2, const float* __restrict__ b2,
                  float* __restrict__ Sa3, float* __restrict__ Sq3, int M) {
    __shared__ float sred[256], qred[256];
    __shared__ float scs[64], shs[64];
    int t = threadIdx.x;
    int w = t >> 6, l = t & 63;
    int dl = l & 15, q4 = l >> 4;

    if (t < 64) {
        float m = Sa2[t] * INVN;
        float v = Sq2[t] * INVN - m * m;
        float s = g2[t] * rsqrtf(v + EPSV);
        scs[t] = s; shs[t] = b2[t] - s * m;
    }
    sred[t] = 0.f; qred[t] = 0.f;
    __syncthreads();

    int m0 = blockIdx.x * 64 + w * 16;
    int row = m0 + dl;
    long arow = (row < M) ? row : (M - 1);
    const ushort* ap0 = x2raw + arow * MIDF + q4 * 8;
    short8 au2[2];
#pragma unroll
    for (int s = 0; s < 2; s++) {
        union { short8 v; ushort u[8]; } raw;
        union { short8 v; unsigned d[4]; } cv;
        raw.v = *(const short8*)(ap0 + s * 32);
        float fv[8];
#pragma unroll
        for (int e = 0; e < 8; e++) {
            int d = s * 32 + q4 * 8 + e;
            float f = bf2f(raw.u[e]) * scs[d] + shs[d];
            fv[e] = (f >= 0.f) ? f : SLOPE * f;
        }
#pragma unroll
        for (int e2 = 0; e2 < 4; e2++)
            cv.d[e2] = cvt_pk_bf16(fv[2 * e2], fv[2 * e2 + 1]);
        au2[s] = cv.v;
    }
    const short8* Bp = (const short8*)Wp + l;
    int rb = q4 * 4;
#pragma unroll
    for (int half = 0; half < 2; half++) {
        float4v acc[8];
#pragma unroll
        for (int j = 0; j < 8; j++) acc[j] = (float4v){0.f, 0.f, 0.f, 0.f};
#pragma unroll
        for (int s = 0; s < 2; s++)
#pragma unroll
            for (int j = 0; j < 8; j++) {
                short8 bf = Bp[(s * 16 + half * 8 + j) * 64];
                acc[j] = __builtin_amdgcn_mfma_f32_16x16x32_bf16(au2[s], bf, acc[j], 0, 0, 0);
            }
#pragma unroll
        for (int j = 0; j < 8; j++) {
            float s = 0.f, q = 0.f;
#pragma unroll
            for (int r = 0; r < 4; r++) {
                float v = ((m0 + rb + r) < M) ? acc[j][r] : 0.f;
                s += v; q += v * v;
            }
            s += __shfl_xor(s, 16); s += __shfl_xor(s, 32);
            q += __shfl_xor(q, 16); q += __shfl_xor(q, 32);
            if (q4 == 0) {
                atomicAdd(&sred[(half * 8 + j) * 16 + dl], s);
                atomicAdd(&qred[(half * 8 + j) * 16 + dl], q);
            }
        }
    }
    __syncthreads();
    atomicAdd(&Sa3[t], sred[t]);
    atomicAdd(&Sq3[t], qred[t]);
}

// ---------- conv3 recompute + final epilogue: x3 tile in LDS, no global x3 ----------
__global__ __launch_bounds__(256)
void k_conv3final(const ushort* __restrict__ x2raw, const ushort* __restrict__ Wp,
                  const ushort* __restrict__ scb, float* __restrict__ out,
                  const float* __restrict__ Sa2, const float* __restrict__ Sq2,
                  const float* __restrict__ g2, const float* __restrict__ b2,
                  const float* __restrict__ a3, const float* __restrict__ q3,
                  const float* __restrict__ g3, const float* __restrict__ b3,
                  const float* __restrict__ aS, const float* __restrict__ qS,
                  const float* __restrict__ gs, const float* __restrict__ bs,
                  int M) {
    __shared__ float scs[64], shs[64];
    __shared__ float s3[256], h3[256], sS[256], hS[256];
    __shared__ __align__(8) ushort x3t[64][256];   // 32 KB bf16 strip
    int t = threadIdx.x;
    int w = t >> 6, l = t & 63;
    int dl = l & 15, q4 = l >> 4;

    if (t < 64) {
        float m = Sa2[t] * INVN;
        float v = Sq2[t] * INVN - m * m;
        float s = g2[t] * rsqrtf(v + EPSV);
        scs[t] = s; shs[t] = b2[t] - s * m;
    }
    {   // BN3 + BN-shortcut coefficients (stats complete: prior kernels on stream)
        float m = a3[t] * INVN;
        float v = q3[t] * INVN - m * m;
        float s = g3[t] * rsqrtf(v + EPSV);
        s3[t] = s; h3[t] = b3[t] - s * m;
        m = aS[t] * INVN;
        v = qS[t] * INVN - m * m;
        s = gs[t] * rsqrtf(v + EPSV);
        sS[t] = s; hS[t] = bs[t] - s * m;
    }
    __syncthreads();

    // ---- phase A: conv3 GEMM recompute (identical accs to k_conv3stats),
    //      x3 bf16 (same f2bf rounding as the old global x3b path) -> LDS ----
    int m0 = blockIdx.x * 64 + w * 16;
    int row = m0 + dl;
    long arow = (row < M) ? row : (M - 1);
    const ushort* ap0 = x2raw + arow * MIDF + q4 * 8;
    short8 au2[2];
#pragma unroll
    for (int s = 0; s < 2; s++) {
        union { short8 v; ushort u[8]; } raw;
        union { short8 v; unsigned d[4]; } cv;
        raw.v = *(const short8*)(ap0 + s * 32);
        float fv[8];
#pragma unroll
        for (int e = 0; e < 8; e++) {
            int d = s * 32 + q4 * 8 + e;
            float f = bf2f(raw.u[e]) * scs[d] + shs[d];
            fv[e] = (f >= 0.f) ? f : SLOPE * f;
        }
#pragma unroll
        for (int e2 = 0; e2 < 4; e2++)
            cv.d[e2] = cvt_pk_bf16(fv[2 * e2], fv[2 * e2 + 1]);
        au2[s] = cv.v;
    }
    const short8* Bp = (const short8*)Wp + l;
    int rb = q4 * 4;
#pragma unroll
    for (int half = 0; half < 2; half++) {
        float4v acc[8];
#pragma unroll
        for (int j = 0; j < 8; j++) acc[j] = (float4v){0.f, 0.f, 0.f, 0.f};
#pragma unroll
        for (int s = 0; s < 2; s++)
#pragma unroll
            for (int j = 0; j < 8; j++) {
                short8 bf = Bp[(s * 16 + half * 8 + j) * 64];
                acc[j] = __builtin_amdgcn_mfma_f32_16x16x32_bf16(au2[s], bf, acc[j], 0, 0, 0);
            }
#pragma unroll
        for (int r = 0; r < 4; r++) {
            int lrow = w * 16 + rb + r;
#pragma unroll
            for (int j = 0; j < 8; j++)
                x3t[lrow][(half * 8 + j) * 16 + dl] = f2bf(acc[j][r]);
        }
    }
    __syncthreads();

    // ---- phase B: epilogue; x3 from LDS, scb/out contiguous ----
#pragma unroll
    for (int it = 0; it < 16; it++) {
        int e = it * 1024 + t * 4;          // 0..16383 over [64][256]
        int lrow = e >> 8;
        int grow = blockIdx.x * 64 + lrow;
        if (grow < M) {
            int col = e & 255;
            ull va = *(const ull*)&x3t[lrow][col];
            ull vb = *(const ull*)(scb + (long)grow * 256 + col);
            float r[4];
#pragma unroll
            for (int j = 0; j < 4; j++) {
                int c = col + j;
                float x = bf2f((ushort)((va >> (16 * j)) & 0xffff)) * s3[c] + h3[c];
                x = (x >= 0.f) ? x : SLOPE * x;
                float sc = bf2f((ushort)((vb >> (16 * j)) & 0xffff)) * sS[c] + hS[c];
                sc = (sc >= 0.f) ? sc : SLOPE * sc;
                float v = x + sc;
                r[j] = (v >= 0.f) ? v : SLOPE * v;
            }
            *(float4*)(out + (long)grow * 256 + col) = (float4){r[0], r[1], r[2], r[3]};
        }
    }
}

extern "C" void kernel_launch(void* const* d_in, const int* in_sizes, int n_in,
                              void* d_out, int out_size, void* d_ws, size_t ws_size,
                              hipStream_t stream) {
    const float* qp   = (const float*)d_in[0];
    const float* sp   = (const float*)d_in[1];
    const int*   nbr  = (const int*)d_in[2];
    const float* feat = (const float*)d_in[3];
    const float* kpp  = (const float*)d_in[4];
    const float* w1   = (const float*)d_in[5];
    const float* g1   = (const float*)d_in[6];
    const float* b1   = (const float*)d_in[7];
    const float* kw   = (const float*)d_in[8];
    const float* g2   = (const float*)d_in[9];
    const float* b2   = (const float*)d_in[10];
    const float* w3   = (const float*)d_in[11];
    const float* g3   = (const float*)d_in[12];
    const float* b3   = (const float*)d_in[13];
    const float* wsw  = (const float*)d_in[14];
    const float* gs   = (const float*)d_in[15];
    const float* bs   = (const float*)d_in[16];
    float* out = (float*)d_out;

    char* base = (char*)d_ws;
    ushort* x1raw = (ushort*)(base + 0);          // 6.4 MB (permuted layout)
    ushort* x2raw = (ushort*)(base + 12800000);   // 6.4 MB
    ushort* scb   = (ushort*)(base + 44800000);   // 25.6 MB (linear)
    ushort* wpC   = (ushort*)(base + 70400000);   // 80 KB
    ushort* wpk   = (ushort*)(base + 70481920);   // 128 KB (K=1024)
    ushort* wp3   = (ushort*)(base + 70612992);   // 32 KB
    float*  st    = (float*)(base + 70645760);
    float* acc1 = st,       *q1 = st + 64;
    float* acc2 = st + 128, *q2 = st + 192;
    float* acc3 = st + 256, *q3 = st + 512;
    float* accS = st + 768, *qS = st + 1024;

    // repack weights + zero stats (block 60) -- memset dispatch eliminated
    k_repack_all<<<61, 256, 0, stream>>>(w1, wsw, wpC, kw, wpk, w3, wp3, st);

    // conv1 + shortcut fused (feat read once); x1 permuted (pre-BN), scb linear
    k_conv1sc<<<782, 256, 0, stream>>>(feat, wpC, x1raw, scb, acc1, q1, accS, qS, NPTS);

    // KPConv with BN1+lrelu fused into the gather path (k_bnx eliminated)
    k_kpconv<<<NPTS / 16, 256, 0, stream>>>(qp, sp, nbr, x1raw, kpp, wpk, x2raw,
                                            acc2, q2, acc1, q1, g1, b1);

    // conv3 stats pass (no x3 store), then recompute + fused final epilogue
    k_conv3stats<<<782, 256, 0, stream>>>(x2raw, wp3, acc2, q2, g2, b2, acc3, q3, NPTS);
    k_conv3final<<<782, 256, 0, stream>>>(x2raw, wp3, scb, out,
                                          acc2, q2, g2, b2, acc3, q3,
                                          g3, b3, accS, qS, gs, bs, NPTS);
}